// Round 1
// baseline (1704.803 us; speedup 1.0000x reference)
//
#include <hip/hip_runtime.h>
#include <math.h>

#define NN 100000
#define EE 3200000
#define ETOT (EE + NN)
#define NEG_SLOPE 0.2f

// ---------------- helpers ----------------
__device__ __forceinline__ float wmax64(float v) {
#pragma unroll
  for (int o = 32; o; o >>= 1) v = fmaxf(v, __shfl_xor(v, o));
  return v;
}
__device__ __forceinline__ float wsum64(float v) {
#pragma unroll
  for (int o = 32; o; o >>= 1) v += __shfl_xor(v, o);
  return v;
}
__device__ __forceinline__ float lrelu(float v) { return v > 0.f ? v : NEG_SLOPE * v; }
__device__ __forceinline__ float elu1(float v) { return v > 0.f ? v : expm1f(v); }

// ---------------- CSR build ----------------
__global__ void k_hist(const int* __restrict__ ei, int* __restrict__ deg) {
  int e = blockIdx.x * 256 + threadIdx.x;
  if (e >= ETOT) return;
  int d = (e < EE) ? ei[EE + e] : (e - EE);
  atomicAdd(&deg[d], 1);
}

// single block, 1024 threads: exclusive scan of deg[NN] -> offs, cursor
__global__ __launch_bounds__(1024) void k_scan(const int* __restrict__ deg,
                                               int* __restrict__ offs,
                                               int* __restrict__ cursor) {
  __shared__ int ts[1024];
  const int tid = threadIdx.x;
  const int PER = (NN + 1023) / 1024;  // 98
  int b = tid * PER;
  int e = b + PER; if (e > NN) e = NN;
  int s = 0;
  for (int i = b; i < e; ++i) s += deg[i];
  ts[tid] = s;
  __syncthreads();
  // Hillis-Steele inclusive scan
  for (int off = 1; off < 1024; off <<= 1) {
    int add = (tid >= off) ? ts[tid - off] : 0;
    __syncthreads();
    ts[tid] += add;
    __syncthreads();
  }
  int running = ts[tid] - s;  // exclusive prefix
  for (int i = b; i < e; ++i) {
    offs[i] = running;
    cursor[i] = running;
    running += deg[i];
  }
  if (tid == 0) offs[NN] = ETOT;
}

__global__ void k_scatter(const int* __restrict__ ei, int* __restrict__ cursor,
                          int* __restrict__ csr_src) {
  int e = blockIdx.x * 256 + threadIdx.x;
  if (e >= ETOT) return;
  int s, d;
  if (e < EE) { s = ei[e]; d = ei[EE + e]; } else { s = e - EE; d = e - EE; }
  int pos = atomicAdd(&cursor[d], 1);
  csr_src[pos] = s;
}

// ---------------- generic fp32 tiled GEMM: C[M,NC] = A[M,K] @ B[K,NC] ----------------
// 64x64 tile per block (256 thr, 4x4 per thread), K chunked by 64.
__global__ __launch_bounds__(256) void k_gemm(const float* __restrict__ A,
                                              const float* __restrict__ B,
                                              float* __restrict__ C,
                                              int M, int K, int NC) {
  __shared__ float AsT[64][68];  // [k][row], pad 68 for aligned conflict-free b128 reads
  __shared__ float Bs[64][64];   // [k][col]
  const int ntile = NC >> 6;
  const int bx = blockIdx.x % ntile;
  const int by = blockIdx.x / ntile;
  const int tid = threadIdx.x;
  const int tx = tid & 15, ty = tid >> 4;
  const int row0 = by * 64;
  float acc[4][4];
#pragma unroll
  for (int i = 0; i < 4; ++i)
#pragma unroll
    for (int j = 0; j < 4; ++j) acc[i][j] = 0.f;

  for (int k0 = 0; k0 < K; k0 += 64) {
#pragma unroll
    for (int i = 0; i < 4; ++i) {
      int q = i * 256 + tid;       // 0..1023 float4s of A chunk
      int r = q >> 4;              // row 0..63
      int k4 = (q & 15) * 4;       // k within chunk
      float4 f = make_float4(0.f, 0.f, 0.f, 0.f);
      int gr = row0 + r;
      if (gr < M) f = *(const float4*)(A + (size_t)gr * K + k0 + k4);
      AsT[k4 + 0][r] = f.x; AsT[k4 + 1][r] = f.y;
      AsT[k4 + 2][r] = f.z; AsT[k4 + 3][r] = f.w;
    }
#pragma unroll
    for (int i = 0; i < 4; ++i) {
      int q = i * 256 + tid;
      int kk = q >> 4;
      int c4 = (q & 15) * 4;
      *(float4*)&Bs[kk][c4] = *(const float4*)(B + (size_t)(k0 + kk) * NC + bx * 64 + c4);
    }
    __syncthreads();
#pragma unroll
    for (int kk = 0; kk < 64; ++kk) {
      float4 a4 = *(float4*)&AsT[kk][ty * 4];
      float4 b4 = *(float4*)&Bs[kk][tx * 4];
      float av[4] = {a4.x, a4.y, a4.z, a4.w};
      float bv[4] = {b4.x, b4.y, b4.z, b4.w};
#pragma unroll
      for (int i = 0; i < 4; ++i)
#pragma unroll
        for (int j = 0; j < 4; ++j) acc[i][j] = fmaf(av[i], bv[j], acc[i][j]);
    }
    __syncthreads();
  }
#pragma unroll
  for (int i = 0; i < 4; ++i) {
    int gr = row0 + ty * 4 + i;
    if (gr < M) {
      float4 o = make_float4(acc[i][0], acc[i][1], acc[i][2], acc[i][3]);
      *(float4*)(C + (size_t)gr * NC + bx * 64 + tx * 4) = o;
    }
  }
}

// ---------------- per-node attention coefficients ----------------
// layer 1: h1[N,256] viewed as [N,4,64]; a_src1/a_dst1 flat [256]
__global__ __launch_bounds__(256) void k_alphas1(const float* __restrict__ h1,
                                                 const float* __restrict__ a_src,
                                                 const float* __restrict__ a_dst,
                                                 float* __restrict__ as_out,
                                                 float* __restrict__ ad_out) {
  int n = blockIdx.x;
  int t = threadIdx.x;
  int lane = t & 63;
  float v = h1[(size_t)n * 256 + t];
  float ps = wsum64(v * a_src[t]);
  float pd = wsum64(v * a_dst[t]);
  if (lane == 0) {
    int h = t >> 6;
    as_out[n * 4 + h] = ps;
    ad_out[n * 4 + h] = pd;
  }
}

// layer 2: h2[N,64], 1 head
__global__ __launch_bounds__(256) void k_alphas2(const float* __restrict__ h2,
                                                 const float* __restrict__ a_src,
                                                 const float* __restrict__ a_dst,
                                                 float* __restrict__ as_out,
                                                 float* __restrict__ ad_out) {
  int n = blockIdx.x * 4 + (threadIdx.x >> 6);
  if (n >= NN) return;
  int lane = threadIdx.x & 63;
  float v = h2[(size_t)n * 64 + lane];
  float ps = wsum64(v * a_src[lane]);
  float pd = wsum64(v * a_dst[lane]);
  if (lane == 0) { as_out[n] = ps; ad_out[n] = pd; }
}

// ---------------- fused attention layer 1 (max + denom + aggregate + bias + ELU) ----
// one wave per dst node; lane l holds float4 l of the 256-wide output row.
__global__ __launch_bounds__(256) void k_attn1(const int* __restrict__ offs,
                                               const int* __restrict__ csr_src,
                                               const float* __restrict__ a_s,
                                               const float* __restrict__ a_d,
                                               const float* __restrict__ h1,
                                               const float* __restrict__ b1,
                                               float* __restrict__ out) {
  int n = (blockIdx.x * 256 + threadIdx.x) >> 6;
  if (n >= NN) return;
  int lane = threadIdx.x & 63;
  int beg = offs[n], end = offs[n + 1];
  const float4 ad = *(const float4*)(a_d + n * 4);
  float4 mx = make_float4(-INFINITY, -INFINITY, -INFINITY, -INFINITY);
  for (int i = beg + lane; i < end; i += 64) {
    int s = csr_src[i];
    float4 as = *(const float4*)(a_s + s * 4);
    mx.x = fmaxf(mx.x, lrelu(as.x + ad.x));
    mx.y = fmaxf(mx.y, lrelu(as.y + ad.y));
    mx.z = fmaxf(mx.z, lrelu(as.z + ad.z));
    mx.w = fmaxf(mx.w, lrelu(as.w + ad.w));
  }
  mx.x = wmax64(mx.x); mx.y = wmax64(mx.y); mx.z = wmax64(mx.z); mx.w = wmax64(mx.w);
  float4 sm = make_float4(0.f, 0.f, 0.f, 0.f);
  for (int i = beg + lane; i < end; i += 64) {
    int s = csr_src[i];
    float4 as = *(const float4*)(a_s + s * 4);
    sm.x += __expf(lrelu(as.x + ad.x) - mx.x);
    sm.y += __expf(lrelu(as.y + ad.y) - mx.y);
    sm.z += __expf(lrelu(as.z + ad.z) - mx.z);
    sm.w += __expf(lrelu(as.w + ad.w) - mx.w);
  }
  sm.x = wsum64(sm.x); sm.y = wsum64(sm.y); sm.z = wsum64(sm.z); sm.w = wsum64(sm.w);

  int h = lane >> 4;  // head for this lane's float4
  float mh = (h == 0) ? mx.x : (h == 1) ? mx.y : (h == 2) ? mx.z : mx.w;
  float dh = (h == 0) ? sm.x : (h == 1) ? sm.y : (h == 2) ? sm.z : sm.w;
  float inv = 1.f / dh;
  float adh = a_d[n * 4 + h];
  const float4* h1f4 = (const float4*)h1;
  float4 acc = make_float4(0.f, 0.f, 0.f, 0.f);
  for (int j = beg; j < end; ++j) {
    int s = csr_src[j];
    float le = lrelu(a_s[s * 4 + h] + adh);
    float w = __expf(le - mh) * inv;
    float4 hv = h1f4[(size_t)s * 64 + lane];
    acc.x = fmaf(hv.x, w, acc.x);
    acc.y = fmaf(hv.y, w, acc.y);
    acc.z = fmaf(hv.z, w, acc.z);
    acc.w = fmaf(hv.w, w, acc.w);
  }
  int c = lane * 4;
  float4 bb = *(const float4*)(b1 + c);
  float4 o;
  o.x = elu1(acc.x + bb.x);
  o.y = elu1(acc.y + bb.y);
  o.z = elu1(acc.z + bb.z);
  o.w = elu1(acc.w + bb.w);
  *(float4*)(out + (size_t)n * 256 + c) = o;
}

// ---------------- fused attention layer 2 + final linear ----------------
__global__ __launch_bounds__(256) void k_attn2(const int* __restrict__ offs,
                                               const int* __restrict__ csr_src,
                                               const float* __restrict__ a_s,
                                               const float* __restrict__ a_d,
                                               const float* __restrict__ h2,
                                               const float* __restrict__ b2,
                                               const float* __restrict__ lin_w,
                                               const float* __restrict__ lin_b,
                                               float* __restrict__ out) {
  int n = (blockIdx.x * 256 + threadIdx.x) >> 6;
  if (n >= NN) return;
  int lane = threadIdx.x & 63;
  int beg = offs[n], end = offs[n + 1];
  float adn = a_d[n];
  float mx = -INFINITY;
  for (int i = beg + lane; i < end; i += 64) {
    int s = csr_src[i];
    mx = fmaxf(mx, lrelu(a_s[s] + adn));
  }
  mx = wmax64(mx);
  float sm = 0.f;
  for (int i = beg + lane; i < end; i += 64) {
    int s = csr_src[i];
    sm += __expf(lrelu(a_s[s] + adn) - mx);
  }
  sm = wsum64(sm);
  float inv = 1.f / sm;
  float acc = 0.f;
  for (int j = beg; j < end; ++j) {
    int s = csr_src[j];
    float w = __expf(lrelu(a_s[s] + adn) - mx) * inv;
    acc = fmaf(h2[(size_t)s * 64 + lane], w, acc);
  }
  float o = elu1(acc + b2[lane]);
  float p0 = wsum64(o * lin_w[lane * 2 + 0]);
  float p1 = wsum64(o * lin_w[lane * 2 + 1]);
  if (lane == 0) {
    out[n * 2 + 0] = p0 + lin_b[0];
    out[n * 2 + 1] = p1 + lin_b[1];
  }
}

// ---------------- launch ----------------
extern "C" void kernel_launch(void* const* d_in, const int* in_sizes, int n_in,
                              void* d_out, int out_size, void* d_ws, size_t ws_size,
                              hipStream_t stream) {
  const float* x      = (const float*)d_in[0];
  const int*   ei     = (const int*)d_in[1];
  const float* W1     = (const float*)d_in[2];
  const float* a_src1 = (const float*)d_in[3];
  const float* a_dst1 = (const float*)d_in[4];
  const float* b1     = (const float*)d_in[5];
  const float* W2     = (const float*)d_in[6];
  const float* a_src2 = (const float*)d_in[7];
  const float* a_dst2 = (const float*)d_in[8];
  const float* b2     = (const float*)d_in[9];
  const float* lin_w  = (const float*)d_in[10];
  const float* lin_b  = (const float*)d_in[11];
  float* outp = (float*)d_out;

  char* w = (char*)d_ws;
  // layout (bytes):
  float* h1   = (float*)(w + 0);            // N*256*4 = 102,400,000 ; reused as h2
  float* h1e  = (float*)(w + 102400000);    // N*256*4
  float* as1  = (float*)(w + 204800000);    // N*4*4
  float* ad1  = (float*)(w + 206400000);    // N*4*4
  float* as2  = (float*)(w + 208000000);    // N*4
  float* ad2  = (float*)(w + 208400000);    // N*4
  int*   deg  = (int*)(w + 208800000);      // N*4
  int*   offs = (int*)(w + 209200000);      // (N+1)*4
  int*   cur  = (int*)(w + 209600128);      // N*4
  int*   csr  = (int*)(w + 210000128);      // ETOT*4
  float* h2   = h1;                          // overlap: h1 dead before gemm2 writes

  const int EB = (ETOT + 255) / 256;  // 12891

  // CSR build
  hipMemsetAsync(deg, 0, NN * sizeof(int), stream);
  k_hist<<<EB, 256, 0, stream>>>(ei, deg);
  k_scan<<<1, 1024, 0, stream>>>(deg, offs, cur);
  k_scatter<<<EB, 256, 0, stream>>>(ei, cur, csr);

  // layer 1
  k_gemm<<<4 * 1563, 256, 0, stream>>>(x, W1, h1, NN, 128, 256);
  k_alphas1<<<NN, 256, 0, stream>>>(h1, a_src1, a_dst1, as1, ad1);
  k_attn1<<<NN / 4, 256, 0, stream>>>(offs, csr, as1, ad1, h1, b1, h1e);

  // layer 2
  k_gemm<<<1 * 1563, 256, 0, stream>>>(h1e, W2, h2, NN, 256, 64);
  k_alphas2<<<NN / 4, 256, 0, stream>>>(h2, a_src2, a_dst2, as2, ad2);
  k_attn2<<<NN / 4, 256, 0, stream>>>(offs, csr, as2, ad2, h2, b2, lin_w, lin_b, outp);
}

// Round 2
// 1487.831 us; speedup vs baseline: 1.1458x; 1.1458x over previous
//
#include <hip/hip_runtime.h>
#include <hip/hip_fp16.h>
#include <math.h>

#define NN 100000
#define EE 3200000
#define ETOT (EE + NN)
#define NEG_SLOPE 0.2f

// ---------------- helpers ----------------
__device__ __forceinline__ float wsum64(float v) {
#pragma unroll
  for (int o = 32; o; o >>= 1) v += __shfl_xor(v, o);
  return v;
}
__device__ __forceinline__ float lrelu(float v) { return v > 0.f ? v : NEG_SLOPE * v; }
__device__ __forceinline__ float elu1(float v) { return v > 0.f ? v : expm1f(v); }

// ---------------- CSR build ----------------
__global__ void k_hist(const int* __restrict__ ei, int* __restrict__ deg) {
  int e = blockIdx.x * 256 + threadIdx.x;
  if (e >= ETOT) return;
  int d = (e < EE) ? ei[EE + e] : (e - EE);
  atomicAdd(&deg[d], 1);
}

__global__ __launch_bounds__(1024) void k_scan(const int* __restrict__ deg,
                                               int* __restrict__ offs,
                                               int* __restrict__ cursor) {
  __shared__ int ts[1024];
  const int tid = threadIdx.x;
  const int PER = (NN + 1023) / 1024;  // 98
  int b = tid * PER;
  int e = b + PER; if (e > NN) e = NN;
  int s = 0;
  for (int i = b; i < e; ++i) s += deg[i];
  ts[tid] = s;
  __syncthreads();
  for (int off = 1; off < 1024; off <<= 1) {
    int add = (tid >= off) ? ts[tid - off] : 0;
    __syncthreads();
    ts[tid] += add;
    __syncthreads();
  }
  int running = ts[tid] - s;
  for (int i = b; i < e; ++i) {
    offs[i] = running;
    cursor[i] = running;
    running += deg[i];
  }
  if (tid == 0) offs[NN] = ETOT;
}

__global__ void k_scatter(const int* __restrict__ ei, int* __restrict__ cursor,
                          int* __restrict__ csr_src) {
  int e = blockIdx.x * 256 + threadIdx.x;
  if (e >= ETOT) return;
  int s, d;
  if (e < EE) { s = ei[e]; d = ei[EE + e]; } else { s = e - EE; d = e - EE; }
  int pos = atomicAdd(&cursor[d], 1);
  csr_src[pos] = s;
}

// ---------------- GEMM1 fused: h1h(fp16) + as1/ad1 from x@W1 ----------------
// 64x64 tile per block, 256 thr, 4x4 per thread. NC=256, K=128. head = bx.
__global__ __launch_bounds__(256) void k_gemm1f(const float* __restrict__ A,
                                                const float* __restrict__ B,
                                                const float* __restrict__ a_src,
                                                const float* __restrict__ a_dst,
                                                __half* __restrict__ h1h,
                                                float* __restrict__ as_out,
                                                float* __restrict__ ad_out) {
  const int M = NN, K = 128, NC = 256;
  __shared__ float AsT[64][68];
  __shared__ float Bs[64][64];
  const int bx = blockIdx.x & 3;       // head / col tile
  const int by = blockIdx.x >> 2;
  const int tid = threadIdx.x;
  const int tx = tid & 15, ty = tid >> 4;
  const int row0 = by * 64;
  float acc[4][4];
#pragma unroll
  for (int i = 0; i < 4; ++i)
#pragma unroll
    for (int j = 0; j < 4; ++j) acc[i][j] = 0.f;

  for (int k0 = 0; k0 < K; k0 += 64) {
#pragma unroll
    for (int i = 0; i < 4; ++i) {
      int q = i * 256 + tid;
      int r = q >> 4;
      int k4 = (q & 15) * 4;
      float4 f = make_float4(0.f, 0.f, 0.f, 0.f);
      int gr = row0 + r;
      if (gr < M) f = *(const float4*)(A + (size_t)gr * K + k0 + k4);
      AsT[k4 + 0][r] = f.x; AsT[k4 + 1][r] = f.y;
      AsT[k4 + 2][r] = f.z; AsT[k4 + 3][r] = f.w;
    }
#pragma unroll
    for (int i = 0; i < 4; ++i) {
      int q = i * 256 + tid;
      int kk = q >> 4;
      int c4 = (q & 15) * 4;
      *(float4*)&Bs[kk][c4] = *(const float4*)(B + (size_t)(k0 + kk) * NC + bx * 64 + c4);
    }
    __syncthreads();
#pragma unroll
    for (int kk = 0; kk < 64; ++kk) {
      float4 a4 = *(float4*)&AsT[kk][ty * 4];
      float4 b4 = *(float4*)&Bs[kk][tx * 4];
      float av[4] = {a4.x, a4.y, a4.z, a4.w};
      float bv[4] = {b4.x, b4.y, b4.z, b4.w};
#pragma unroll
      for (int i = 0; i < 4; ++i)
#pragma unroll
        for (int j = 0; j < 4; ++j) acc[i][j] = fmaf(av[i], bv[j], acc[i][j]);
    }
    __syncthreads();
  }
  // epilogue: fp16 store + alpha dots
#pragma unroll
  for (int i = 0; i < 4; ++i) {
    int gr = row0 + ty * 4 + i;
    float ps = 0.f, pd = 0.f;
#pragma unroll
    for (int j = 0; j < 4; ++j) {
      ps = fmaf(acc[i][j], a_src[bx * 64 + tx * 4 + j], ps);
      pd = fmaf(acc[i][j], a_dst[bx * 64 + tx * 4 + j], pd);
    }
#pragma unroll
    for (int o = 1; o < 16; o <<= 1) { ps += __shfl_xor(ps, o); pd += __shfl_xor(pd, o); }
    if (gr < M) {
      if (tx == 0) { as_out[gr * 4 + bx] = ps; ad_out[gr * 4 + bx] = pd; }
      __half2 p01 = __floats2half2_rn(acc[i][0], acc[i][1]);
      __half2 p23 = __floats2half2_rn(acc[i][2], acc[i][3]);
      uint2 pk;
      pk.x = __builtin_bit_cast(unsigned, p01);
      pk.y = __builtin_bit_cast(unsigned, p23);
      *(uint2*)(h1h + (size_t)gr * 256 + bx * 64 + tx * 4) = pk;
    }
  }
}

// ---------------- GEMM2 fused: h2h(fp16) + as2/ad2 from h1e@W2 ----------------
// NC=64, K=256, single col tile.
__global__ __launch_bounds__(256) void k_gemm2f(const float* __restrict__ A,
                                                const float* __restrict__ B,
                                                const float* __restrict__ a_src,
                                                const float* __restrict__ a_dst,
                                                __half* __restrict__ h2h,
                                                float* __restrict__ as_out,
                                                float* __restrict__ ad_out) {
  const int M = NN, K = 256, NC = 64;
  __shared__ float AsT[64][68];
  __shared__ float Bs[64][64];
  const int by = blockIdx.x;
  const int tid = threadIdx.x;
  const int tx = tid & 15, ty = tid >> 4;
  const int row0 = by * 64;
  float acc[4][4];
#pragma unroll
  for (int i = 0; i < 4; ++i)
#pragma unroll
    for (int j = 0; j < 4; ++j) acc[i][j] = 0.f;

  for (int k0 = 0; k0 < K; k0 += 64) {
#pragma unroll
    for (int i = 0; i < 4; ++i) {
      int q = i * 256 + tid;
      int r = q >> 4;
      int k4 = (q & 15) * 4;
      float4 f = make_float4(0.f, 0.f, 0.f, 0.f);
      int gr = row0 + r;
      if (gr < M) f = *(const float4*)(A + (size_t)gr * K + k0 + k4);
      AsT[k4 + 0][r] = f.x; AsT[k4 + 1][r] = f.y;
      AsT[k4 + 2][r] = f.z; AsT[k4 + 3][r] = f.w;
    }
#pragma unroll
    for (int i = 0; i < 4; ++i) {
      int q = i * 256 + tid;
      int kk = q >> 4;
      int c4 = (q & 15) * 4;
      *(float4*)&Bs[kk][c4] = *(const float4*)(B + (size_t)(k0 + kk) * NC + c4);
    }
    __syncthreads();
#pragma unroll
    for (int kk = 0; kk < 64; ++kk) {
      float4 a4 = *(float4*)&AsT[kk][ty * 4];
      float4 b4 = *(float4*)&Bs[kk][tx * 4];
      float av[4] = {a4.x, a4.y, a4.z, a4.w};
      float bv[4] = {b4.x, b4.y, b4.z, b4.w};
#pragma unroll
      for (int i = 0; i < 4; ++i)
#pragma unroll
        for (int j = 0; j < 4; ++j) acc[i][j] = fmaf(av[i], bv[j], acc[i][j]);
    }
    __syncthreads();
  }
#pragma unroll
  for (int i = 0; i < 4; ++i) {
    int gr = row0 + ty * 4 + i;
    float ps = 0.f, pd = 0.f;
#pragma unroll
    for (int j = 0; j < 4; ++j) {
      ps = fmaf(acc[i][j], a_src[tx * 4 + j], ps);
      pd = fmaf(acc[i][j], a_dst[tx * 4 + j], pd);
    }
#pragma unroll
    for (int o = 1; o < 16; o <<= 1) { ps += __shfl_xor(ps, o); pd += __shfl_xor(pd, o); }
    if (gr < M) {
      if (tx == 0) { as_out[gr] = ps; ad_out[gr] = pd; }
      __half2 p01 = __floats2half2_rn(acc[i][0], acc[i][1]);
      __half2 p23 = __floats2half2_rn(acc[i][2], acc[i][3]);
      uint2 pk;
      pk.x = __builtin_bit_cast(unsigned, p01);
      pk.y = __builtin_bit_cast(unsigned, p23);
      *(uint2*)(h2h + (size_t)gr * 64 + tx * 4) = pk;
    }
  }
}

// ---------------- fused attention layer 1 (denom + aggregate + bias + ELU) ----
// one wave per dst node; lane l holds feature chunk l*4..l*4+3 (head = l>>4).
__global__ __launch_bounds__(256) void k_attn1(const int* __restrict__ offs,
                                               const int* __restrict__ csr_src,
                                               const float* __restrict__ a_s,
                                               const float* __restrict__ a_d,
                                               const __half* __restrict__ h1h,
                                               const float* __restrict__ b1,
                                               float* __restrict__ out) {
  int n = (blockIdx.x * 256 + threadIdx.x) >> 6;
  if (n >= NN) return;
  int lane = threadIdx.x & 63;
  int beg = offs[n], end = offs[n + 1];
  const float4 ad = *(const float4*)(a_d + n * 4);
  float4 sm = make_float4(0.f, 0.f, 0.f, 0.f);
  for (int i = beg + lane; i < end; i += 64) {
    int s = csr_src[i];
    float4 as = *(const float4*)(a_s + s * 4);
    sm.x += __expf(lrelu(as.x + ad.x));
    sm.y += __expf(lrelu(as.y + ad.y));
    sm.z += __expf(lrelu(as.z + ad.z));
    sm.w += __expf(lrelu(as.w + ad.w));
  }
  sm.x = wsum64(sm.x); sm.y = wsum64(sm.y); sm.z = wsum64(sm.z); sm.w = wsum64(sm.w);

  int h = lane >> 4;
  float adh = (h & 2) ? ((h & 1) ? ad.w : ad.z) : ((h & 1) ? ad.y : ad.x);
  float dh  = (h & 2) ? ((h & 1) ? sm.w : sm.z) : ((h & 1) ? sm.y : sm.x);
  float inv = 1.f / dh;
  float4 acc = make_float4(0.f, 0.f, 0.f, 0.f);
  for (int j = beg; j < end; ++j) {
    int s = csr_src[j];
    float w = __expf(lrelu(a_s[s * 4 + h] + adh)) * inv;
    uint2 r = *(const uint2*)(h1h + (size_t)s * 256 + lane * 4);
    float2 f0 = __half22float2(__builtin_bit_cast(__half2, r.x));
    float2 f1 = __half22float2(__builtin_bit_cast(__half2, r.y));
    acc.x = fmaf(f0.x, w, acc.x);
    acc.y = fmaf(f0.y, w, acc.y);
    acc.z = fmaf(f1.x, w, acc.z);
    acc.w = fmaf(f1.y, w, acc.w);
  }
  int c = lane * 4;
  float4 bb = *(const float4*)(b1 + c);
  float4 o;
  o.x = elu1(acc.x + bb.x);
  o.y = elu1(acc.y + bb.y);
  o.z = elu1(acc.z + bb.z);
  o.w = elu1(acc.w + bb.w);
  *(float4*)(out + (size_t)n * 256 + c) = o;
}

// ---------------- fused attention layer 2 + final linear ----------------
__global__ __launch_bounds__(256) void k_attn2(const int* __restrict__ offs,
                                               const int* __restrict__ csr_src,
                                               const float* __restrict__ a_s,
                                               const float* __restrict__ a_d,
                                               const __half* __restrict__ h2h,
                                               const float* __restrict__ b2,
                                               const float* __restrict__ lin_w,
                                               const float* __restrict__ lin_b,
                                               float* __restrict__ out) {
  int n = (blockIdx.x * 256 + threadIdx.x) >> 6;
  if (n >= NN) return;
  int lane = threadIdx.x & 63;
  int beg = offs[n], end = offs[n + 1];
  float adn = a_d[n];
  float sm = 0.f;
  for (int i = beg + lane; i < end; i += 64) {
    int s = csr_src[i];
    sm += __expf(lrelu(a_s[s] + adn));
  }
  sm = wsum64(sm);
  float inv = 1.f / sm;
  float acc = 0.f;
  for (int j = beg; j < end; ++j) {
    int s = csr_src[j];
    float w = __expf(lrelu(a_s[s] + adn)) * inv;
    acc = fmaf(__half2float(h2h[(size_t)s * 64 + lane]), w, acc);
  }
  float o = elu1(acc + b2[lane]);
  float p0 = wsum64(o * lin_w[lane * 2 + 0]);
  float p1 = wsum64(o * lin_w[lane * 2 + 1]);
  if (lane == 0) {
    out[n * 2 + 0] = p0 + lin_b[0];
    out[n * 2 + 1] = p1 + lin_b[1];
  }
}

// ---------------- launch ----------------
extern "C" void kernel_launch(void* const* d_in, const int* in_sizes, int n_in,
                              void* d_out, int out_size, void* d_ws, size_t ws_size,
                              hipStream_t stream) {
  const float* x      = (const float*)d_in[0];
  const int*   ei     = (const int*)d_in[1];
  const float* W1     = (const float*)d_in[2];
  const float* a_src1 = (const float*)d_in[3];
  const float* a_dst1 = (const float*)d_in[4];
  const float* b1     = (const float*)d_in[5];
  const float* W2     = (const float*)d_in[6];
  const float* a_src2 = (const float*)d_in[7];
  const float* a_dst2 = (const float*)d_in[8];
  const float* b2     = (const float*)d_in[9];
  const float* lin_w  = (const float*)d_in[10];
  const float* lin_b  = (const float*)d_in[11];
  float* outp = (float*)d_out;

  char* w = (char*)d_ws;
  __half* h1h = (__half*)(w + 0);            // N*256*2 = 51,200,000
  float*  h1e = (float*)(w + 51200000);      // N*256*4 = 102,400,000
  __half* h2h = (__half*)(w + 153600000);    // N*64*2  = 12,800,000
  float*  as1 = (float*)(w + 166400000);     // N*4*4
  float*  ad1 = (float*)(w + 168000000);     // N*4*4
  float*  as2 = (float*)(w + 169600000);     // N*4
  float*  ad2 = (float*)(w + 170000000);     // N*4
  int*    deg = (int*)(w + 170400000);       // N*4
  int*    offs = (int*)(w + 170800000);      // (N+1)*4
  int*    cur = (int*)(w + 171200128);       // N*4
  int*    csr = (int*)(w + 171600128);       // ETOT*4

  const int EB = (ETOT + 255) / 256;

  // CSR build
  hipMemsetAsync(deg, 0, NN * sizeof(int), stream);
  k_hist<<<EB, 256, 0, stream>>>(ei, deg);
  k_scan<<<1, 1024, 0, stream>>>(deg, offs, cur);
  k_scatter<<<EB, 256, 0, stream>>>(ei, cur, csr);

  // layer 1
  k_gemm1f<<<4 * 1563, 256, 0, stream>>>(x, W1, a_src1, a_dst1, h1h, as1, ad1);
  k_attn1<<<NN / 4, 256, 0, stream>>>(offs, csr, as1, ad1, h1h, b1, h1e);

  // layer 2
  k_gemm2f<<<1563, 256, 0, stream>>>(h1e, W2, a_src2, a_dst2, h2h, as2, ad2);
  k_attn2<<<NN / 4, 256, 0, stream>>>(offs, csr, as2, ad2, h2h, b2, lin_w, lin_b, outp);
}

// Round 3
// 1107.797 us; speedup vs baseline: 1.5389x; 1.3431x over previous
//
#include <hip/hip_runtime.h>
#include <hip/hip_fp16.h>
#include <math.h>

#define NN 100000
#define EE 3200000
#define ETOT (EE + NN)
#define NEG_SLOPE 0.2f
#define DMAX 96

typedef _Float16 half8 __attribute__((ext_vector_type(8)));
typedef _Float16 half4v __attribute__((ext_vector_type(4)));
typedef float floatx4 __attribute__((ext_vector_type(4)));

// ---------------- helpers ----------------
__device__ __forceinline__ float wsum64(float v) {
#pragma unroll
  for (int o = 32; o; o >>= 1) v += __shfl_xor(v, o);
  return v;
}
__device__ __forceinline__ float lrelu(float v) { return v > 0.f ? v : NEG_SLOPE * v; }
__device__ __forceinline__ float elu1(float v) { return v > 0.f ? v : expm1f(v); }

// ---------------- CSR build ----------------
__global__ void k_hist(const int* __restrict__ ei, int* __restrict__ deg) {
  int e = blockIdx.x * 256 + threadIdx.x;
  if (e >= ETOT) return;
  int d = (e < EE) ? ei[EE + e] : (e - EE);
  atomicAdd(&deg[d], 1);
}

__global__ __launch_bounds__(1024) void k_scan(const int* __restrict__ deg,
                                               int* __restrict__ offs,
                                               int* __restrict__ cursor) {
  __shared__ int ts[1024];
  const int tid = threadIdx.x;
  const int PER = (NN + 1023) / 1024;  // 98
  int b = tid * PER;
  int e = b + PER; if (e > NN) e = NN;
  int s = 0;
  for (int i = b; i < e; ++i) s += deg[i];
  ts[tid] = s;
  __syncthreads();
  for (int off = 1; off < 1024; off <<= 1) {
    int add = (tid >= off) ? ts[tid - off] : 0;
    __syncthreads();
    ts[tid] += add;
    __syncthreads();
  }
  int running = ts[tid] - s;
  for (int i = b; i < e; ++i) {
    offs[i] = running;
    cursor[i] = running;
    running += deg[i];
  }
  if (tid == 0) offs[NN] = ETOT;
}

__global__ void k_scatter(const int* __restrict__ ei, int* __restrict__ cursor,
                          int* __restrict__ csr_src) {
  int e = blockIdx.x * 256 + threadIdx.x;
  if (e >= ETOT) return;
  int s, d;
  if (e < EE) { s = ei[e]; d = ei[EE + e]; } else { s = e - EE; d = e - EE; }
  int pos = atomicAdd(&cursor[d], 1);
  csr_src[pos] = s;
}

// ---------------- weight prep: fp32 -> fp16 transposed ----------------
// W1t[n][k] = W1[k][n]  (256x128); W2t[n][k] = W2[k][n] (64x256)
__global__ void k_prep(const float* __restrict__ W1, const float* __restrict__ W2,
                       _Float16* __restrict__ W1t, _Float16* __restrict__ W2t) {
  int idx = blockIdx.x * 256 + threadIdx.x;
  if (idx < 32768) {
    int n = idx >> 7, k = idx & 127;
    W1t[idx] = (_Float16)W1[k * 256 + n];
  } else {
    int j = idx - 32768;
    int n = j >> 8, k = j & 255;
    W2t[j] = (_Float16)W2[k * 64 + n];
  }
}

// ---------------- GEMM1 (MFMA fp16): h1h + as1/ad1 from x@W1 ----------------
// block = 64 rows x 64 cols (col tile == head bx). 4 waves, wave = 16-row strip.
__global__ __launch_bounds__(256) void k_gemm1m(const float* __restrict__ x,
                                                const _Float16* __restrict__ W1t,
                                                const float* __restrict__ a_src,
                                                const float* __restrict__ a_dst,
                                                _Float16* __restrict__ h1h,
                                                float* __restrict__ as_out,
                                                float* __restrict__ ad_out) {
  __shared__ _Float16 As[64][136];   // [row][k] pad 136: 2-way-free bank pattern
  __shared__ _Float16 Wt[64][136];   // [n][k]
  const int bx = blockIdx.x & 3;     // head / 64-col tile
  const int by = blockIdx.x >> 2;
  const int tid = threadIdx.x;
  const int row0 = by * 64;
  // stage A (fp32 -> fp16): 64x128
#pragma unroll
  for (int i = 0; i < 8; ++i) {
    int idx = i * 256 + tid;          // 0..2047 float4-groups
    int r = idx >> 5;                 // 0..63
    int c4 = (idx & 31) * 4;          // 0..124
    int gr = row0 + r;
    float4 f = make_float4(0.f, 0.f, 0.f, 0.f);
    if (gr < NN) f = *(const float4*)(x + (size_t)gr * 128 + c4);
    half4v h; h[0] = (_Float16)f.x; h[1] = (_Float16)f.y; h[2] = (_Float16)f.z; h[3] = (_Float16)f.w;
    *(half4v*)&As[r][c4] = h;
  }
  // stage Wt (already fp16-transposed in global): rows bx*64..+63 of W1t
#pragma unroll
  for (int i = 0; i < 4; ++i) {
    int idx = i * 256 + tid;          // 0..1023 half8-groups
    int r = idx >> 4;                 // 0..63
    int g = idx & 15;
    *(half8*)&Wt[r][g * 8] = *(const half8*)(W1t + (size_t)(bx * 64 + r) * 128 + g * 8);
  }
  __syncthreads();

  const int wid = tid >> 6, lane = tid & 63;
  const int m16 = lane & 15, quad = lane >> 4;
  floatx4 acc[4];
#pragma unroll
  for (int nt = 0; nt < 4; ++nt) acc[nt] = (floatx4){0.f, 0.f, 0.f, 0.f};
#pragma unroll
  for (int ks = 0; ks < 4; ++ks) {
    half8 av = *(half8*)&As[wid * 16 + m16][ks * 32 + quad * 8];
#pragma unroll
    for (int nt = 0; nt < 4; ++nt) {
      half8 bv = *(half8*)&Wt[nt * 16 + m16][ks * 32 + quad * 8];
      acc[nt] = __builtin_amdgcn_mfma_f32_16x16x32_f16(av, bv, acc[nt], 0, 0, 0);
    }
  }
  // epilogue: alpha dots + fp16 store
  float asr[4], adr[4];
#pragma unroll
  for (int nt = 0; nt < 4; ++nt) {
    asr[nt] = a_src[bx * 64 + nt * 16 + m16];
    adr[nt] = a_dst[bx * 64 + nt * 16 + m16];
  }
#pragma unroll
  for (int r = 0; r < 4; ++r) {
    float ps = 0.f, pd = 0.f;
#pragma unroll
    for (int nt = 0; nt < 4; ++nt) {
      ps = fmaf(acc[nt][r], asr[nt], ps);
      pd = fmaf(acc[nt][r], adr[nt], pd);
    }
#pragma unroll
    for (int o = 1; o < 16; o <<= 1) { ps += __shfl_xor(ps, o); pd += __shfl_xor(pd, o); }
    int gr = row0 + wid * 16 + quad * 4 + r;
    if (gr < NN) {
      if (m16 == 0) { as_out[gr * 4 + bx] = ps; ad_out[gr * 4 + bx] = pd; }
#pragma unroll
      for (int nt = 0; nt < 4; ++nt)
        h1h[(size_t)gr * 256 + bx * 64 + nt * 16 + m16] = (_Float16)acc[nt][r];
    }
  }
}

// ---------------- GEMM2 (MFMA fp16): h2h + as2/ad2 from h1e@W2 ----------------
// block = 64 rows x 64 cols (all of N=64), K=256 in 2 chunks of 128.
__global__ __launch_bounds__(256) void k_gemm2m(const _Float16* __restrict__ h1e,
                                                const _Float16* __restrict__ W2t,
                                                const float* __restrict__ a_src,
                                                const float* __restrict__ a_dst,
                                                _Float16* __restrict__ h2h,
                                                float* __restrict__ as_out,
                                                float* __restrict__ ad_out) {
  __shared__ _Float16 As2[64][136];
  __shared__ _Float16 Wt2[64][264];
  const int by = blockIdx.x;
  const int tid = threadIdx.x;
  const int row0 = by * 64;
  // stage Wt2 fully (64 x 256)
#pragma unroll
  for (int i = 0; i < 8; ++i) {
    int idx = i * 256 + tid;          // 0..2047 half8-groups
    int r = idx >> 5;                 // 0..63
    int g = idx & 31;
    *(half8*)&Wt2[r][g * 8] = *(const half8*)(W2t + (size_t)r * 256 + g * 8);
  }
  const int wid = tid >> 6, lane = tid & 63;
  const int m16 = lane & 15, quad = lane >> 4;
  floatx4 acc[4];
#pragma unroll
  for (int nt = 0; nt < 4; ++nt) acc[nt] = (floatx4){0.f, 0.f, 0.f, 0.f};

  for (int kc = 0; kc < 2; ++kc) {
#pragma unroll
    for (int i = 0; i < 4; ++i) {
      int idx = i * 256 + tid;        // 0..1023 half8-groups
      int r = idx >> 4;               // 0..63
      int g = idx & 15;
      int gr = row0 + r;
      half8 v = {0, 0, 0, 0, 0, 0, 0, 0};
      if (gr < NN) v = *(const half8*)(h1e + (size_t)gr * 256 + kc * 128 + g * 8);
      *(half8*)&As2[r][g * 8] = v;
    }
    __syncthreads();
#pragma unroll
    for (int ks = 0; ks < 4; ++ks) {
      half8 av = *(half8*)&As2[wid * 16 + m16][ks * 32 + quad * 8];
#pragma unroll
      for (int nt = 0; nt < 4; ++nt) {
        half8 bv = *(half8*)&Wt2[nt * 16 + m16][kc * 128 + ks * 32 + quad * 8];
        acc[nt] = __builtin_amdgcn_mfma_f32_16x16x32_f16(av, bv, acc[nt], 0, 0, 0);
      }
    }
    __syncthreads();
  }
  float asr[4], adr[4];
#pragma unroll
  for (int nt = 0; nt < 4; ++nt) {
    asr[nt] = a_src[nt * 16 + m16];
    adr[nt] = a_dst[nt * 16 + m16];
  }
#pragma unroll
  for (int r = 0; r < 4; ++r) {
    float ps = 0.f, pd = 0.f;
#pragma unroll
    for (int nt = 0; nt < 4; ++nt) {
      ps = fmaf(acc[nt][r], asr[nt], ps);
      pd = fmaf(acc[nt][r], adr[nt], pd);
    }
#pragma unroll
    for (int o = 1; o < 16; o <<= 1) { ps += __shfl_xor(ps, o); pd += __shfl_xor(pd, o); }
    int gr = row0 + wid * 16 + quad * 4 + r;
    if (gr < NN) {
      if (m16 == 0) { as_out[gr] = ps; ad_out[gr] = pd; }
#pragma unroll
      for (int nt = 0; nt < 4; ++nt)
        h2h[(size_t)gr * 64 + nt * 16 + m16] = (_Float16)acc[nt][r];
    }
  }
}

// ---------------- fused attention layer 1 -> h1e (fp16) ----------------
// one wave per dst node, 4 nodes/block. Phase 1: alphas -> LDS. Phase 2: unrolled gather.
__global__ __launch_bounds__(256) void k_attn1(const int* __restrict__ offs,
                                               const int* __restrict__ csr_src,
                                               const float* __restrict__ a_s,
                                               const float* __restrict__ a_d,
                                               const _Float16* __restrict__ h1h,
                                               const float* __restrict__ b1,
                                               _Float16* __restrict__ h1e) {
  __shared__ float alpha[4][DMAX][4];
  __shared__ int sidx[4][DMAX];
  const int wid = threadIdx.x >> 6;
  const int n = blockIdx.x * 4 + wid;
  const int lane = threadIdx.x & 63;
  const int beg = offs[n], deg = offs[n + 1] - beg;
  const float4 ad = *(const float4*)(a_d + n * 4);
  float4 sm = make_float4(0.f, 0.f, 0.f, 0.f);
  for (int d = lane; d < deg; d += 64) {
    int s = csr_src[beg + d];
    float4 as = *(const float4*)(a_s + s * 4);
    float e0 = __expf(lrelu(as.x + ad.x));
    float e1 = __expf(lrelu(as.y + ad.y));
    float e2 = __expf(lrelu(as.z + ad.z));
    float e3 = __expf(lrelu(as.w + ad.w));
    sm.x += e0; sm.y += e1; sm.z += e2; sm.w += e3;
    if (d < DMAX) {
      sidx[wid][d] = s;
      float4 al = make_float4(e0, e1, e2, e3);
      *(float4*)&alpha[wid][d][0] = al;
    }
  }
  sm.x = wsum64(sm.x); sm.y = wsum64(sm.y); sm.z = wsum64(sm.z); sm.w = wsum64(sm.w);
  __syncthreads();

  const int h = lane >> 4;
  float adh = (h & 2) ? ((h & 1) ? ad.w : ad.z) : ((h & 1) ? ad.y : ad.x);
  float dh  = (h & 2) ? ((h & 1) ? sm.w : sm.z) : ((h & 1) ? sm.y : sm.x);
  float inv = 1.f / dh;
  float4 acc = make_float4(0.f, 0.f, 0.f, 0.f);
  const int dlim = deg < DMAX ? deg : DMAX;
  int d = 0;
  for (; d + 4 <= dlim; d += 4) {
    int s0 = sidx[wid][d + 0], s1 = sidx[wid][d + 1];
    int s2 = sidx[wid][d + 2], s3 = sidx[wid][d + 3];
    float w0 = alpha[wid][d + 0][h] * inv;
    float w1 = alpha[wid][d + 1][h] * inv;
    float w2 = alpha[wid][d + 2][h] * inv;
    float w3 = alpha[wid][d + 3][h] * inv;
    half4v r0 = *(const half4v*)(h1h + (size_t)s0 * 256 + lane * 4);
    half4v r1 = *(const half4v*)(h1h + (size_t)s1 * 256 + lane * 4);
    half4v r2 = *(const half4v*)(h1h + (size_t)s2 * 256 + lane * 4);
    half4v r3 = *(const half4v*)(h1h + (size_t)s3 * 256 + lane * 4);
    acc.x = fmaf((float)r0[0], w0, acc.x); acc.y = fmaf((float)r0[1], w0, acc.y);
    acc.z = fmaf((float)r0[2], w0, acc.z); acc.w = fmaf((float)r0[3], w0, acc.w);
    acc.x = fmaf((float)r1[0], w1, acc.x); acc.y = fmaf((float)r1[1], w1, acc.y);
    acc.z = fmaf((float)r1[2], w1, acc.z); acc.w = fmaf((float)r1[3], w1, acc.w);
    acc.x = fmaf((float)r2[0], w2, acc.x); acc.y = fmaf((float)r2[1], w2, acc.y);
    acc.z = fmaf((float)r2[2], w2, acc.z); acc.w = fmaf((float)r2[3], w2, acc.w);
    acc.x = fmaf((float)r3[0], w3, acc.x); acc.y = fmaf((float)r3[1], w3, acc.y);
    acc.z = fmaf((float)r3[2], w3, acc.z); acc.w = fmaf((float)r3[3], w3, acc.w);
  }
  for (; d < dlim; ++d) {
    int s = sidx[wid][d];
    float w = alpha[wid][d][h] * inv;
    half4v r = *(const half4v*)(h1h + (size_t)s * 256 + lane * 4);
    acc.x = fmaf((float)r[0], w, acc.x); acc.y = fmaf((float)r[1], w, acc.y);
    acc.z = fmaf((float)r[2], w, acc.z); acc.w = fmaf((float)r[3], w, acc.w);
  }
  for (; d < deg; ++d) {  // overflow fallback (deg > DMAX): never in practice
    int s = csr_src[beg + d];
    float w = __expf(lrelu(a_s[s * 4 + h] + adh)) * inv;
    half4v r = *(const half4v*)(h1h + (size_t)s * 256 + lane * 4);
    acc.x = fmaf((float)r[0], w, acc.x); acc.y = fmaf((float)r[1], w, acc.y);
    acc.z = fmaf((float)r[2], w, acc.z); acc.w = fmaf((float)r[3], w, acc.w);
  }
  const int c = lane * 4;
  float4 bb = *(const float4*)(b1 + c);
  half4v o;
  o[0] = (_Float16)elu1(acc.x + bb.x);
  o[1] = (_Float16)elu1(acc.y + bb.y);
  o[2] = (_Float16)elu1(acc.z + bb.z);
  o[3] = (_Float16)elu1(acc.w + bb.w);
  *(half4v*)(h1e + (size_t)n * 256 + c) = o;
}

// ---------------- fused attention layer 2 + final linear ----------------
__global__ __launch_bounds__(256) void k_attn2(const int* __restrict__ offs,
                                               const int* __restrict__ csr_src,
                                               const float* __restrict__ a_s,
                                               const float* __restrict__ a_d,
                                               const _Float16* __restrict__ h2h,
                                               const float* __restrict__ b2,
                                               const float* __restrict__ lin_w,
                                               const float* __restrict__ lin_b,
                                               float* __restrict__ out) {
  __shared__ float alpha2[4][DMAX];
  __shared__ int sidx2[4][DMAX];
  const int wid = threadIdx.x >> 6;
  const int n = blockIdx.x * 4 + wid;
  const int lane = threadIdx.x & 63;
  const int beg = offs[n], deg = offs[n + 1] - beg;
  const float adn = a_d[n];
  float sm = 0.f;
  for (int d = lane; d < deg; d += 64) {
    int s = csr_src[beg + d];
    float e = __expf(lrelu(a_s[s] + adn));
    sm += e;
    if (d < DMAX) { sidx2[wid][d] = s; alpha2[wid][d] = e; }
  }
  sm = wsum64(sm);
  __syncthreads();
  float inv = 1.f / sm;
  float acc = 0.f;
  const int dlim = deg < DMAX ? deg : DMAX;
  int d = 0;
  for (; d + 4 <= dlim; d += 4) {
    int s0 = sidx2[wid][d + 0], s1 = sidx2[wid][d + 1];
    int s2 = sidx2[wid][d + 2], s3 = sidx2[wid][d + 3];
    float w0 = alpha2[wid][d + 0] * inv;
    float w1 = alpha2[wid][d + 1] * inv;
    float w2 = alpha2[wid][d + 2] * inv;
    float w3 = alpha2[wid][d + 3] * inv;
    float v0 = (float)h2h[(size_t)s0 * 64 + lane];
    float v1 = (float)h2h[(size_t)s1 * 64 + lane];
    float v2 = (float)h2h[(size_t)s2 * 64 + lane];
    float v3 = (float)h2h[(size_t)s3 * 64 + lane];
    acc = fmaf(v0, w0, acc); acc = fmaf(v1, w1, acc);
    acc = fmaf(v2, w2, acc); acc = fmaf(v3, w3, acc);
  }
  for (; d < dlim; ++d) {
    acc = fmaf((float)h2h[(size_t)sidx2[wid][d] * 64 + lane], alpha2[wid][d] * inv, acc);
  }
  for (; d < deg; ++d) {  // overflow fallback
    int s = csr_src[beg + d];
    float w = __expf(lrelu(a_s[s] + adn)) * inv;
    acc = fmaf((float)h2h[(size_t)s * 64 + lane], w, acc);
  }
  float o = elu1(acc + b2[lane]);
  float p0 = wsum64(o * lin_w[lane * 2 + 0]);
  float p1 = wsum64(o * lin_w[lane * 2 + 1]);
  if (lane == 0) {
    out[n * 2 + 0] = p0 + lin_b[0];
    out[n * 2 + 1] = p1 + lin_b[1];
  }
}

// ---------------- launch ----------------
extern "C" void kernel_launch(void* const* d_in, const int* in_sizes, int n_in,
                              void* d_out, int out_size, void* d_ws, size_t ws_size,
                              hipStream_t stream) {
  const float* x      = (const float*)d_in[0];
  const int*   ei     = (const int*)d_in[1];
  const float* W1     = (const float*)d_in[2];
  const float* a_src1 = (const float*)d_in[3];
  const float* a_dst1 = (const float*)d_in[4];
  const float* b1     = (const float*)d_in[5];
  const float* W2     = (const float*)d_in[6];
  const float* a_src2 = (const float*)d_in[7];
  const float* a_dst2 = (const float*)d_in[8];
  const float* b2     = (const float*)d_in[9];
  const float* lin_w  = (const float*)d_in[10];
  const float* lin_b  = (const float*)d_in[11];
  float* outp = (float*)d_out;

  char* w = (char*)d_ws;
  _Float16* h1h = (_Float16*)(w + 0);            // N*256*2 = 51,200,000
  _Float16* h1e = (_Float16*)(w + 51200000);     // N*256*2 = 51,200,000
  _Float16* h2h = (_Float16*)(w + 102400000);    // N*64*2  = 12,800,000
  _Float16* W1t = (_Float16*)(w + 115200000);    // 32768*2 = 65,536
  _Float16* W2t = (_Float16*)(w + 115265536);    // 16384*2 = 32,768
  float*  as1 = (float*)(w + 115298304);         // N*4*4
  float*  ad1 = (float*)(w + 116898304);         // N*4*4
  float*  as2 = (float*)(w + 118498304);         // N*4
  float*  ad2 = (float*)(w + 118898304);         // N*4
  int*    deg = (int*)(w + 119298304);           // N*4
  int*    offs = (int*)(w + 119698304);          // (N+1)*4
  int*    cur = (int*)(w + 120098432);           // N*4
  int*    csr = (int*)(w + 120498432);           // ETOT*4

  const int EB = (ETOT + 255) / 256;

  // CSR build + weight prep
  hipMemsetAsync(deg, 0, NN * sizeof(int), stream);
  k_hist<<<EB, 256, 0, stream>>>(ei, deg);
  k_scan<<<1, 1024, 0, stream>>>(deg, offs, cur);
  k_scatter<<<EB, 256, 0, stream>>>(ei, cur, csr);
  k_prep<<<192, 256, 0, stream>>>(W1, W2, W1t, W2t);

  // layer 1
  k_gemm1m<<<4 * 1563, 256, 0, stream>>>(x, W1t, a_src1, a_dst1, h1h, as1, ad1);
  k_attn1<<<NN / 4, 256, 0, stream>>>(offs, csr, as1, ad1, h1h, b1, h1e);

  // layer 2
  k_gemm2m<<<1563, 256, 0, stream>>>(h1e, W2t, a_src2, a_dst2, h2h, as2, ad2);
  k_attn2<<<NN / 4, 256, 0, stream>>>(offs, csr, as2, ad2, h2h, b2, lin_w, lin_b, outp);
}

// Round 4
// 615.980 us; speedup vs baseline: 2.7676x; 1.7984x over previous
//
#include <hip/hip_runtime.h>
#include <hip/hip_fp16.h>
#include <math.h>

#define NN 100000
#define EE 3200000
#define ETOT (EE + NN)
#define NEG_SLOPE 0.2f
#define DMAX 96
#define CHUNK 4096
#define NB0 ((ETOT + CHUNK - 1) / CHUNK)  // 806
#define RB 391                            // 256 * 391 >= NN
#define EDCAP 16384

typedef _Float16 half8 __attribute__((ext_vector_type(8)));
typedef _Float16 half4v __attribute__((ext_vector_type(4)));
typedef float floatx4 __attribute__((ext_vector_type(4)));

// ---------------- helpers ----------------
__device__ __forceinline__ float wsum64(float v) {
#pragma unroll
  for (int o = 32; o; o >>= 1) v += __shfl_xor(v, o);
  return v;
}
__device__ __forceinline__ float lrelu(float v) { return v > 0.f ? v : NEG_SLOPE * v; }
__device__ __forceinline__ float elu1(float v) { return v > 0.f ? v : expm1f(v); }

// ---------------- pass0: coarse histogram (256 buckets) + weight prep ----------------
__global__ __launch_bounds__(256) void k_pass0(const int* __restrict__ ei,
                                               int* __restrict__ chist,
                                               const float* __restrict__ W1,
                                               const float* __restrict__ W2,
                                               _Float16* __restrict__ W1t,
                                               _Float16* __restrict__ W2t) {
  int b = blockIdx.x;
  if (b >= NB0) {  // weight prep blocks
    int idx = (b - NB0) * 256 + threadIdx.x;
    if (idx < 32768) {
      int n = idx >> 7, k = idx & 127;
      W1t[idx] = (_Float16)W1[k * 256 + n];
    } else {
      int j = idx - 32768;
      int n = j >> 8, k = j & 255;
      W2t[j] = (_Float16)W2[k * 64 + n];
    }
    return;
  }
  __shared__ int h[256];
  h[threadIdx.x] = 0;
  __syncthreads();
  int base = b * CHUNK;
  int lim = base + CHUNK; if (lim > ETOT) lim = ETOT;
  for (int i = base + threadIdx.x; i < lim; i += 256) {
    int d = (i < EE) ? ei[EE + i] : (i - EE);
    atomicAdd(&h[(unsigned)d / (unsigned)RB], 1);
  }
  __syncthreads();
  if (h[threadIdx.x]) atomicAdd(&chist[threadIdx.x], h[threadIdx.x]);
}

// ---------------- coarse scan (256 values) ----------------
__global__ __launch_bounds__(256) void k_cscan(const int* __restrict__ chist,
                                               int* __restrict__ coffs,
                                               int* __restrict__ ccur) {
  __shared__ int ts[256];
  int t = threadIdx.x;
  int v = chist[t];
  ts[t] = v;
  __syncthreads();
  for (int o = 1; o < 256; o <<= 1) {
    int add = (t >= o) ? ts[t - o] : 0;
    __syncthreads();
    ts[t] += add;
    __syncthreads();
  }
  int excl = ts[t] - v;
  coffs[t] = excl;
  ccur[t] = excl;
  if (t == 0) coffs[256] = ETOT;
}

// ---------------- pass1: bucketize edges by coarse dst range ----------------
// payload: (dloc:9 | src:17) packed in u32
__global__ __launch_bounds__(256) void k_pass1(const int* __restrict__ ei,
                                               int* __restrict__ ccur,
                                               unsigned* __restrict__ ebuf) {
  __shared__ unsigned vv[CHUNK];
  __shared__ unsigned short cbv[CHUNK];
  __shared__ int h[256];
  __shared__ int cur[256];
  int t = threadIdx.x;
  h[t] = 0;
  __syncthreads();
  int base = blockIdx.x * CHUNK;
  int lim = base + CHUNK; if (lim > ETOT) lim = ETOT;
  int cnt = lim - base;
  for (int i = t; i < cnt; i += 256) {
    int e = base + i;
    int s, d;
    if (e < EE) { s = ei[e]; d = ei[EE + e]; } else { s = e - EE; d = s; }
    unsigned cb = (unsigned)d / (unsigned)RB;
    unsigned dloc = (unsigned)d - cb * (unsigned)RB;
    vv[i] = (dloc << 17) | (unsigned)s;
    cbv[i] = (unsigned short)cb;
    atomicAdd(&h[cb], 1);
  }
  __syncthreads();
  if (h[t]) cur[t] = atomicAdd(&ccur[t], h[t]);
  __syncthreads();
  for (int i = t; i < cnt; i += 256) {
    int cb = cbv[i];
    int pos = atomicAdd(&cur[cb], 1);
    ebuf[pos] = vv[i];
  }
}

// ---------------- pass2: per-bucket exact placement via LDS cursors; emits offs+csr ----
__global__ __launch_bounds__(256) void k_pass2(const unsigned* __restrict__ ebuf,
                                               const int* __restrict__ coffs,
                                               int* __restrict__ offs,
                                               int* __restrict__ csr) {
  __shared__ unsigned ed[EDCAP];
  __shared__ int hist[RB];
  __shared__ int cur[RB];
  int b = blockIdx.x, t = threadIdx.x;
  int d0 = b * RB;
  int rb = NN - d0; if (rb > RB) rb = RB;
  int cbeg = coffs[b], cend = coffs[b + 1];
  int cnt = cend - cbeg;
  for (int j = t; j < rb; j += 256) hist[j] = 0;
  __syncthreads();
  for (int i = t; i < cnt; i += 256) {
    unsigned v = ebuf[cbeg + i];
    if (i < EDCAP) ed[i] = v;
    atomicAdd(&hist[v >> 17], 1);
  }
  __syncthreads();
  if (t == 0) {
    int run = cbeg;
    for (int j = 0; j < rb; ++j) { cur[j] = run; run += hist[j]; }
  }
  __syncthreads();
  for (int j = t; j < rb; j += 256) offs[d0 + j] = cur[j];
  if (b == 0 && t == 0) offs[NN] = ETOT;
  __syncthreads();
  int lim = cnt < EDCAP ? cnt : EDCAP;
  for (int i = t; i < lim; i += 256) {
    unsigned v = ed[i];
    int pos = atomicAdd(&cur[v >> 17], 1);
    csr[pos] = (int)(v & 0x1FFFFu);
  }
  for (int i = EDCAP + t; i < cnt; i += 256) {  // overflow fallback (never in practice)
    unsigned v = ebuf[cbeg + i];
    int pos = atomicAdd(&cur[v >> 17], 1);
    csr[pos] = (int)(v & 0x1FFFFu);
  }
}

// ---------------- GEMM1 (MFMA fp16): h1h + as1/ad1 from x@W1 ----------------
__global__ __launch_bounds__(256) void k_gemm1m(const float* __restrict__ x,
                                                const _Float16* __restrict__ W1t,
                                                const float* __restrict__ a_src,
                                                const float* __restrict__ a_dst,
                                                _Float16* __restrict__ h1h,
                                                float* __restrict__ as_out,
                                                float* __restrict__ ad_out) {
  __shared__ _Float16 As[64][136];
  __shared__ _Float16 Wt[64][136];
  const int bx = blockIdx.x & 3;
  const int by = blockIdx.x >> 2;
  const int tid = threadIdx.x;
  const int row0 = by * 64;
#pragma unroll
  for (int i = 0; i < 8; ++i) {
    int idx = i * 256 + tid;
    int r = idx >> 5;
    int c4 = (idx & 31) * 4;
    int gr = row0 + r;
    float4 f = make_float4(0.f, 0.f, 0.f, 0.f);
    if (gr < NN) f = *(const float4*)(x + (size_t)gr * 128 + c4);
    half4v h; h[0] = (_Float16)f.x; h[1] = (_Float16)f.y; h[2] = (_Float16)f.z; h[3] = (_Float16)f.w;
    *(half4v*)&As[r][c4] = h;
  }
#pragma unroll
  for (int i = 0; i < 4; ++i) {
    int idx = i * 256 + tid;
    int r = idx >> 4;
    int g = idx & 15;
    *(half8*)&Wt[r][g * 8] = *(const half8*)(W1t + (size_t)(bx * 64 + r) * 128 + g * 8);
  }
  __syncthreads();

  const int wid = tid >> 6, lane = tid & 63;
  const int m16 = lane & 15, quad = lane >> 4;
  floatx4 acc[4];
#pragma unroll
  for (int nt = 0; nt < 4; ++nt) acc[nt] = (floatx4){0.f, 0.f, 0.f, 0.f};
#pragma unroll
  for (int ks = 0; ks < 4; ++ks) {
    half8 av = *(half8*)&As[wid * 16 + m16][ks * 32 + quad * 8];
#pragma unroll
    for (int nt = 0; nt < 4; ++nt) {
      half8 bv = *(half8*)&Wt[nt * 16 + m16][ks * 32 + quad * 8];
      acc[nt] = __builtin_amdgcn_mfma_f32_16x16x32_f16(av, bv, acc[nt], 0, 0, 0);
    }
  }
  float asr[4], adr[4];
#pragma unroll
  for (int nt = 0; nt < 4; ++nt) {
    asr[nt] = a_src[bx * 64 + nt * 16 + m16];
    adr[nt] = a_dst[bx * 64 + nt * 16 + m16];
  }
#pragma unroll
  for (int r = 0; r < 4; ++r) {
    float ps = 0.f, pd = 0.f;
#pragma unroll
    for (int nt = 0; nt < 4; ++nt) {
      ps = fmaf(acc[nt][r], asr[nt], ps);
      pd = fmaf(acc[nt][r], adr[nt], pd);
    }
#pragma unroll
    for (int o = 1; o < 16; o <<= 1) { ps += __shfl_xor(ps, o); pd += __shfl_xor(pd, o); }
    int gr = row0 + wid * 16 + quad * 4 + r;
    if (gr < NN) {
      if (m16 == 0) { as_out[gr * 4 + bx] = ps; ad_out[gr * 4 + bx] = pd; }
#pragma unroll
      for (int nt = 0; nt < 4; ++nt)
        h1h[(size_t)gr * 256 + bx * 64 + nt * 16 + m16] = (_Float16)acc[nt][r];
    }
  }
}

// ---------------- GEMM2 (MFMA fp16): h2h + as2/ad2 from h1e@W2 ----------------
__global__ __launch_bounds__(256) void k_gemm2m(const _Float16* __restrict__ h1e,
                                                const _Float16* __restrict__ W2t,
                                                const float* __restrict__ a_src,
                                                const float* __restrict__ a_dst,
                                                _Float16* __restrict__ h2h,
                                                float* __restrict__ as_out,
                                                float* __restrict__ ad_out) {
  __shared__ _Float16 As2[64][136];
  __shared__ _Float16 Wt2[64][264];
  const int by = blockIdx.x;
  const int tid = threadIdx.x;
  const int row0 = by * 64;
#pragma unroll
  for (int i = 0; i < 8; ++i) {
    int idx = i * 256 + tid;
    int r = idx >> 5;
    int g = idx & 31;
    *(half8*)&Wt2[r][g * 8] = *(const half8*)(W2t + (size_t)r * 256 + g * 8);
  }
  const int wid = tid >> 6, lane = tid & 63;
  const int m16 = lane & 15, quad = lane >> 4;
  floatx4 acc[4];
#pragma unroll
  for (int nt = 0; nt < 4; ++nt) acc[nt] = (floatx4){0.f, 0.f, 0.f, 0.f};

  for (int kc = 0; kc < 2; ++kc) {
#pragma unroll
    for (int i = 0; i < 4; ++i) {
      int idx = i * 256 + tid;
      int r = idx >> 4;
      int g = idx & 15;
      int gr = row0 + r;
      half8 v = {0, 0, 0, 0, 0, 0, 0, 0};
      if (gr < NN) v = *(const half8*)(h1e + (size_t)gr * 256 + kc * 128 + g * 8);
      *(half8*)&As2[r][g * 8] = v;
    }
    __syncthreads();
#pragma unroll
    for (int ks = 0; ks < 4; ++ks) {
      half8 av = *(half8*)&As2[wid * 16 + m16][ks * 32 + quad * 8];
#pragma unroll
      for (int nt = 0; nt < 4; ++nt) {
        half8 bv = *(half8*)&Wt2[nt * 16 + m16][kc * 128 + ks * 32 + quad * 8];
        acc[nt] = __builtin_amdgcn_mfma_f32_16x16x32_f16(av, bv, acc[nt], 0, 0, 0);
      }
    }
    __syncthreads();
  }
  float asr[4], adr[4];
#pragma unroll
  for (int nt = 0; nt < 4; ++nt) {
    asr[nt] = a_src[nt * 16 + m16];
    adr[nt] = a_dst[nt * 16 + m16];
  }
#pragma unroll
  for (int r = 0; r < 4; ++r) {
    float ps = 0.f, pd = 0.f;
#pragma unroll
    for (int nt = 0; nt < 4; ++nt) {
      ps = fmaf(acc[nt][r], asr[nt], ps);
      pd = fmaf(acc[nt][r], adr[nt], pd);
    }
#pragma unroll
    for (int o = 1; o < 16; o <<= 1) { ps += __shfl_xor(ps, o); pd += __shfl_xor(pd, o); }
    int gr = row0 + wid * 16 + quad * 4 + r;
    if (gr < NN) {
      if (m16 == 0) { as_out[gr] = ps; ad_out[gr] = pd; }
#pragma unroll
      for (int nt = 0; nt < 4; ++nt)
        h2h[(size_t)gr * 64 + nt * 16 + m16] = (_Float16)acc[nt][r];
    }
  }
}

// ---------------- fused attention layer 1 -> h1e (fp16) ----------------
__global__ __launch_bounds__(256) void k_attn1(const int* __restrict__ offs,
                                               const int* __restrict__ csr_src,
                                               const float* __restrict__ a_s,
                                               const float* __restrict__ a_d,
                                               const _Float16* __restrict__ h1h,
                                               const float* __restrict__ b1,
                                               _Float16* __restrict__ h1e) {
  __shared__ float alpha[4][DMAX][4];
  __shared__ int sidx[4][DMAX];
  const int wid = threadIdx.x >> 6;
  const int n = blockIdx.x * 4 + wid;
  const int lane = threadIdx.x & 63;
  const int beg = offs[n], deg = offs[n + 1] - beg;
  const float4 ad = *(const float4*)(a_d + n * 4);
  float4 sm = make_float4(0.f, 0.f, 0.f, 0.f);
  for (int d = lane; d < deg; d += 64) {
    int s = csr_src[beg + d];
    float4 as = *(const float4*)(a_s + s * 4);
    float e0 = __expf(lrelu(as.x + ad.x));
    float e1 = __expf(lrelu(as.y + ad.y));
    float e2 = __expf(lrelu(as.z + ad.z));
    float e3 = __expf(lrelu(as.w + ad.w));
    sm.x += e0; sm.y += e1; sm.z += e2; sm.w += e3;
    if (d < DMAX) {
      sidx[wid][d] = s;
      float4 al = make_float4(e0, e1, e2, e3);
      *(float4*)&alpha[wid][d][0] = al;
    }
  }
  sm.x = wsum64(sm.x); sm.y = wsum64(sm.y); sm.z = wsum64(sm.z); sm.w = wsum64(sm.w);
  __syncthreads();

  const int h = lane >> 4;
  float adh = (h & 2) ? ((h & 1) ? ad.w : ad.z) : ((h & 1) ? ad.y : ad.x);
  float dh  = (h & 2) ? ((h & 1) ? sm.w : sm.z) : ((h & 1) ? sm.y : sm.x);
  float inv = 1.f / dh;
  float4 acc = make_float4(0.f, 0.f, 0.f, 0.f);
  const int dlim = deg < DMAX ? deg : DMAX;
  int d = 0;
  for (; d + 8 <= dlim; d += 8) {
    int ss[8]; float ww[8];
#pragma unroll
    for (int u = 0; u < 8; ++u) {
      ss[u] = sidx[wid][d + u];
      ww[u] = alpha[wid][d + u][h] * inv;
    }
    half4v rr[8];
#pragma unroll
    for (int u = 0; u < 8; ++u)
      rr[u] = *(const half4v*)(h1h + (size_t)ss[u] * 256 + lane * 4);
#pragma unroll
    for (int u = 0; u < 8; ++u) {
      acc.x = fmaf((float)rr[u][0], ww[u], acc.x);
      acc.y = fmaf((float)rr[u][1], ww[u], acc.y);
      acc.z = fmaf((float)rr[u][2], ww[u], acc.z);
      acc.w = fmaf((float)rr[u][3], ww[u], acc.w);
    }
  }
  for (; d < dlim; ++d) {
    int s = sidx[wid][d];
    float w = alpha[wid][d][h] * inv;
    half4v r = *(const half4v*)(h1h + (size_t)s * 256 + lane * 4);
    acc.x = fmaf((float)r[0], w, acc.x); acc.y = fmaf((float)r[1], w, acc.y);
    acc.z = fmaf((float)r[2], w, acc.z); acc.w = fmaf((float)r[3], w, acc.w);
  }
  for (; d < deg; ++d) {  // overflow fallback (deg > DMAX): never in practice
    int s = csr_src[beg + d];
    float w = __expf(lrelu(a_s[s * 4 + h] + adh)) * inv;
    half4v r = *(const half4v*)(h1h + (size_t)s * 256 + lane * 4);
    acc.x = fmaf((float)r[0], w, acc.x); acc.y = fmaf((float)r[1], w, acc.y);
    acc.z = fmaf((float)r[2], w, acc.z); acc.w = fmaf((float)r[3], w, acc.w);
  }
  const int c = lane * 4;
  float4 bb = *(const float4*)(b1 + c);
  half4v o;
  o[0] = (_Float16)elu1(acc.x + bb.x);
  o[1] = (_Float16)elu1(acc.y + bb.y);
  o[2] = (_Float16)elu1(acc.z + bb.z);
  o[3] = (_Float16)elu1(acc.w + bb.w);
  *(half4v*)(h1e + (size_t)n * 256 + c) = o;
}

// ---------------- fused attention layer 2 + final linear ----------------
__global__ __launch_bounds__(256) void k_attn2(const int* __restrict__ offs,
                                               const int* __restrict__ csr_src,
                                               const float* __restrict__ a_s,
                                               const float* __restrict__ a_d,
                                               const _Float16* __restrict__ h2h,
                                               const float* __restrict__ b2,
                                               const float* __restrict__ lin_w,
                                               const float* __restrict__ lin_b,
                                               float* __restrict__ out) {
  __shared__ float alpha2[4][DMAX];
  __shared__ int sidx2[4][DMAX];
  const int wid = threadIdx.x >> 6;
  const int n = blockIdx.x * 4 + wid;
  const int lane = threadIdx.x & 63;
  const int beg = offs[n], deg = offs[n + 1] - beg;
  const float adn = a_d[n];
  float sm = 0.f;
  for (int d = lane; d < deg; d += 64) {
    int s = csr_src[beg + d];
    float e = __expf(lrelu(a_s[s] + adn));
    sm += e;
    if (d < DMAX) { sidx2[wid][d] = s; alpha2[wid][d] = e; }
  }
  sm = wsum64(sm);
  __syncthreads();
  float inv = 1.f / sm;
  float acc = 0.f;
  const int dlim = deg < DMAX ? deg : DMAX;
  int d = 0;
  for (; d + 8 <= dlim; d += 8) {
    int ss[8]; float ww[8]; float vv[8];
#pragma unroll
    for (int u = 0; u < 8; ++u) {
      ss[u] = sidx2[wid][d + u];
      ww[u] = alpha2[wid][d + u] * inv;
    }
#pragma unroll
    for (int u = 0; u < 8; ++u)
      vv[u] = (float)h2h[(size_t)ss[u] * 64 + lane];
#pragma unroll
    for (int u = 0; u < 8; ++u) acc = fmaf(vv[u], ww[u], acc);
  }
  for (; d < dlim; ++d) {
    acc = fmaf((float)h2h[(size_t)sidx2[wid][d] * 64 + lane], alpha2[wid][d] * inv, acc);
  }
  for (; d < deg; ++d) {  // overflow fallback
    int s = csr_src[beg + d];
    float w = __expf(lrelu(a_s[s] + adn)) * inv;
    acc = fmaf((float)h2h[(size_t)s * 64 + lane], w, acc);
  }
  float o = elu1(acc + b2[lane]);
  float p0 = wsum64(o * lin_w[lane * 2 + 0]);
  float p1 = wsum64(o * lin_w[lane * 2 + 1]);
  if (lane == 0) {
    out[n * 2 + 0] = p0 + lin_b[0];
    out[n * 2 + 1] = p1 + lin_b[1];
  }
}

// ---------------- launch ----------------
extern "C" void kernel_launch(void* const* d_in, const int* in_sizes, int n_in,
                              void* d_out, int out_size, void* d_ws, size_t ws_size,
                              hipStream_t stream) {
  const float* x      = (const float*)d_in[0];
  const int*   ei     = (const int*)d_in[1];
  const float* W1     = (const float*)d_in[2];
  const float* a_src1 = (const float*)d_in[3];
  const float* a_dst1 = (const float*)d_in[4];
  const float* b1     = (const float*)d_in[5];
  const float* W2     = (const float*)d_in[6];
  const float* a_src2 = (const float*)d_in[7];
  const float* a_dst2 = (const float*)d_in[8];
  const float* b2     = (const float*)d_in[9];
  const float* lin_w  = (const float*)d_in[10];
  const float* lin_b  = (const float*)d_in[11];
  float* outp = (float*)d_out;

  char* w = (char*)d_ws;
  _Float16* h1h = (_Float16*)(w + 0);            // 51,200,000
  _Float16* h1e = (_Float16*)(w + 51200000);     // 51,200,000
  _Float16* h2h = (_Float16*)(w + 102400000);    // 12,800,000
  _Float16* W1t = (_Float16*)(w + 115200000);    // 65,536
  _Float16* W2t = (_Float16*)(w + 115265536);    // 32,768
  float*  as1 = (float*)(w + 115298304);         // 1,600,000
  float*  ad1 = (float*)(w + 116898304);         // 1,600,000
  float*  as2 = (float*)(w + 118498304);         // 400,000
  float*  ad2 = (float*)(w + 118898304);         // 400,000
  int*    offs = (int*)(w + 119298304);          // 400,004 (+pad)
  unsigned* ebuf = (unsigned*)(w + 119698432);   // 13,200,000
  int*    csr = (int*)(w + 132898432);           // 13,200,000
  int*    chist = (int*)(w + 146098432);         // 1,024
  int*    coffs = (int*)(w + 146099456);         // 1,028
  int*    ccur  = (int*)(w + 146100484);         // 1,024

  // CSR build (two-level counting sort) + weight prep
  hipMemsetAsync(chist, 0, 256 * sizeof(int), stream);
  k_pass0<<<NB0 + 192, 256, 0, stream>>>(ei, chist, W1, W2, W1t, W2t);
  k_cscan<<<1, 256, 0, stream>>>(chist, coffs, ccur);
  k_pass1<<<NB0, 256, 0, stream>>>(ei, ccur, ebuf);
  k_pass2<<<256, 256, 0, stream>>>(ebuf, coffs, offs, csr);

  // layer 1
  k_gemm1m<<<4 * 1563, 256, 0, stream>>>(x, W1t, a_src1, a_dst1, h1h, as1, ad1);
  k_attn1<<<NN / 4, 256, 0, stream>>>(offs, csr, as1, ad1, h1h, b1, h1e);

  // layer 2
  k_gemm2m<<<1563, 256, 0, stream>>>(h1e, W2t, a_src2, a_dst2, h2h, as2, ad2);
  k_attn2<<<NN / 4, 256, 0, stream>>>(offs, csr, as2, ad2, h2h, b2, lin_w, lin_b, outp);
}